// Round 17
// baseline (228.332 us; speedup 1.0000x reference)
//
#include <hip/hip_runtime.h>
#include <hip/hip_fp16.h>
#include <math.h>

#define T_LEN   720
#define V_DIM   64
#define KBINS   4
#define NKNOTS  4
#define BLOCK   256     // 4 waves; 16 v-groups x 16 t-phases; t = 16i + s
#define TSLICE  45
#define NW      4
#define PIPE    4

// ws float offsets
#define WS_TABH 0       // [720] uint4 = 8 fp16 {c0..3,s0..3} per t (2880 floats)
#define WS_SR   2880    // [4][64] Re(scale)-1, [k][v]
#define WS_SI   3136    // [4][64] Im(scale),   [k][v]
#define WS_KN   3392    // [4][64] clipped knots, [n][v]

// ---- Kernel A: one-time tables ----
__global__ __launch_bounds__(256) void precompute_kernel(
    const float* __restrict__ a, const float* __restrict__ phi,
    const float* __restrict__ env_knots, const int* __restrict__ k_bins,
    float* __restrict__ ws)
{
    int id = blockIdx.x * 256 + threadIdx.x;
    if (id < T_LEN) {
        int t = id;
        __half h[8];
        #pragma unroll
        for (int k = 0; k < 4; ++k) {
            int kb = k_bins[k];
            int m  = (kb * t) % T_LEN;                       // exact integer angle reduction
            float th = (float)m * 0.00872664625997164788f;   // 2*pi/720
            float sn, cs;
            sincosf(th, &sn, &cs);
            h[k]     = __float2half_rn(cs);
            h[4 + k] = __float2half_rn(sn);
        }
        ((uint4*)(ws + WS_TABH))[t] = *(const uint4*)(&h[0]);
    } else if (id < T_LEN + V_DIM * KBINS) {
        int e = id - T_LEN;                                  // v*4+k
        int v = e >> 2, k = e & 3;
        float amp = 1.0f + a[e];
        float ph  = tanhf(phi[e]) * 0.25f;
        float sp, cp;
        sincosf(ph, &sp, &cp);
        ws[WS_SR + k * V_DIM + v] = amp * cp - 1.0f;
        ws[WS_SI + k * V_DIM + v] = amp * sp;
    } else if (id < T_LEN + V_DIM * KBINS + V_DIM * NKNOTS) {
        int e = id - T_LEN - V_DIM * KBINS;                  // v*4+n
        int v = e >> 2, n = e & 3;
        ws[WS_KN + n * V_DIM + v] = fminf(fmaxf(env_knots[e], 0.5f), 1.5f);
    }
}

// ---- K1: pure-read streamer; DFT coef per (b,v,k) -> staged in out[b] rows 0..7 ----
__global__ __launch_bounds__(BLOCK) void coef_kernel(
    const float* __restrict__ y,
    const float* __restrict__ ws,
    float* __restrict__ coefOut)      // == out; batch b's coef at out[b*46080 .. +512)
{
    __shared__ __align__(16) uint4 tabh[T_LEN];   // 11,520 B fp16 trig
    __shared__ float red[16][NW][33];             //  8,448 B

    const int tid  = threadIdx.x;
    const int b    = blockIdx.x;
    const int g    = tid & 15;
    const int s    = tid >> 4;       // 0..15
    const int lane = tid & 63;
    const int w    = tid >> 6;       // 0..3

    for (int e = tid; e < T_LEN; e += BLOCK)
        tabh[e] = ((const uint4*)(ws + WS_TABH))[e];
    __syncthreads();

    const size_t base = (size_t)b * (T_LEN * V_DIM) + (size_t)(g << 2);
    float accre[4][4], accim[4][4];
    #pragma unroll
    for (int j = 0; j < 4; ++j)
        #pragma unroll
        for (int k = 0; k < 4; ++k) { accre[j][k] = 0.f; accim[j][k] = 0.f; }

    float4 yv[PIPE];
    #pragma unroll
    for (int i0 = 0; i0 < PIPE; ++i0)
        yv[i0] = *(const float4*)(y + base + (size_t)(16 * i0 + s) * V_DIM);
    #pragma unroll
    for (int i = 0; i < TSLICE; ++i) {
        const int t = 16 * i + s;
        float4 cur = yv[i & 3];
        if (i + PIPE < TSLICE)
            yv[i & 3] = *(const float4*)(y + base + (size_t)(16 * (i + PIPE) + s) * V_DIM);
        uint4 hp = tabh[t];
        const __half* h = (const __half*)&hp;
        const float cs[4] = {__half2float(h[0]), __half2float(h[1]),
                             __half2float(h[2]), __half2float(h[3])};
        const float sn[4] = {__half2float(h[4]), __half2float(h[5]),
                             __half2float(h[6]), __half2float(h[7])};
        const float yj[4] = {cur.x, cur.y, cur.z, cur.w};
        #pragma unroll
        for (int j = 0; j < 4; ++j)
            #pragma unroll
            for (int k = 0; k < 4; ++k) {
                accre[j][k] = fmaf(yj[j], cs[k], accre[j][k]);
                accim[j][k] = fmaf(yj[j], sn[k], accim[j][k]);
            }
    }

    #pragma unroll
    for (int j = 0; j < 4; ++j)
        #pragma unroll
        for (int k = 0; k < 4; ++k) {
            float r = accre[j][k], im = accim[j][k];
            r  += __shfl_xor(r, 16, 64);  r  += __shfl_xor(r, 32, 64);
            im += __shfl_xor(im, 16, 64); im += __shfl_xor(im, 32, 64);
            accre[j][k] = r; accim[j][k] = im;
        }
    if (lane < 16) {   // lane == g
        #pragma unroll
        for (int j = 0; j < 4; ++j)
            #pragma unroll
            for (int k = 0; k < 4; ++k) {
                red[lane][w][j * 8 + k]     = accre[j][k];
                red[lane][w][j * 8 + 4 + k] = accim[j][k];
            }
    }
    __syncthreads();
    {   // fixed-order deterministic sum + (scale-1) transform; contiguous stores
        const int e = tid;            // e = k*64 + v
        const int k = e >> 6, v = e & 63;
        const int gg = v >> 2, j = v & 3;
        float cr = 0.f, ci = 0.f;
        #pragma unroll
        for (int ww = 0; ww < NW; ++ww) {
            cr += red[gg][ww][j * 8 + k];
            ci += red[gg][ww][j * 8 + 4 + k];
        }
        float sr = ws[WS_SR + e];
        float si = ws[WS_SI + e];
        const float sc = 2.0f / (float)T_LEN;
        float* cb = coefOut + (size_t)b * (T_LEN * V_DIM);
        cb[e]       = (cr * sr + ci * si) * sc;   // Re C * 2/T
        cb[256 + e] = (cr * si - ci * sr) * sc;   // Im C * 2/T
    }
}

// ---- K2: copy-with-FMA streamer; b processed in REVERSE for L3 hits ----
__global__ __launch_bounds__(BLOCK) void apply_kernel(
    const float* __restrict__ y,
    const float* __restrict__ ws,
    float* __restrict__ out,
    int B)
{
    __shared__ __align__(16) uint4 tabh[T_LEN];   // 11,520 B

    const int tid = threadIdx.x;
    const int b   = B - 1 - blockIdx.x;           // reverse: tail of y is L3-hot after K1
    const int g   = tid & 15;
    const int s   = tid >> 4;

    for (int e = tid; e < T_LEN; e += BLOCK)
        tabh[e] = ((const uint4*)(ws + WS_TABH))[e];

    // coef staged in out[b] rows 0..7 — read BEFORE the barrier, overwritten after
    const float* cb = out + (size_t)b * (T_LEN * V_DIM);
    float cre[4][4], cim[4][4];   // [k][j]
    #pragma unroll
    for (int k = 0; k < 4; ++k) {
        float4 r4 = *(const float4*)(cb + k * 64 + (g << 2));
        float4 i4 = *(const float4*)(cb + 256 + k * 64 + (g << 2));
        cre[k][0] = r4.x; cre[k][1] = r4.y; cre[k][2] = r4.z; cre[k][3] = r4.w;
        cim[k][0] = i4.x; cim[k][1] = i4.y; cim[k][2] = i4.z; cim[k][3] = i4.w;
    }
    float kn[4][4];               // [n][j] knots in registers
    #pragma unroll
    for (int n = 0; n < 4; ++n) {
        float4 k4 = *(const float4*)(ws + WS_KN + n * V_DIM + (g << 2));
        kn[n][0] = k4.x; kn[n][1] = k4.y; kn[n][2] = k4.z; kn[n][3] = k4.w;
    }
    __syncthreads();   // all coef reads done before any store overwrites them

    const size_t base = (size_t)b * (T_LEN * V_DIM) + (size_t)(g << 2);
    const float posScale = 3.0f / 719.0f;

    float4 zv[PIPE];
    #pragma unroll
    for (int i0 = 0; i0 < PIPE; ++i0)
        zv[i0] = *(const float4*)(y + base + (size_t)(16 * i0 + s) * V_DIM);
    #pragma unroll
    for (int i = 0; i < TSLICE; ++i) {
        const int t = 16 * i + s;
        float4 cur = zv[i & 3];
        if (i + PIPE < TSLICE)
            zv[i & 3] = *(const float4*)(y + base + (size_t)(16 * (i + PIPE) + s) * V_DIM);
        uint4 hp = tabh[t];
        const __half* h = (const __half*)&hp;
        const float cs[4] = {__half2float(h[0]), __half2float(h[1]),
                             __half2float(h[2]), __half2float(h[3])};
        const float sn[4] = {__half2float(h[4]), __half2float(h[5]),
                             __half2float(h[6]), __half2float(h[7])};
        float pos = (float)t * posScale;
        int idx = (int)pos; idx = idx > 2 ? 2 : idx;
        float frac = pos - (float)idx;
        const float yj[4] = {cur.x, cur.y, cur.z, cur.w};
        float4 o;
        #pragma unroll
        for (int j = 0; j < 4; ++j) {
            float d = 0.f;
            #pragma unroll
            for (int k = 0; k < 4; ++k)
                d = fmaf(cre[k][j], cs[k], fmaf(-cim[k][j], sn[k], d));
            float e0 = (idx == 0) ? kn[0][j] : ((idx == 1) ? kn[1][j] : kn[2][j]);
            float e1 = (idx == 0) ? kn[1][j] : ((idx == 1) ? kn[2][j] : kn[3][j]);
            float env = fmaf(e1 - e0, frac, e0);
            ((float*)&o)[j] = (yj[j] + d) * env;
        }
        *(float4*)(out + base + (size_t)t * V_DIM) = o;
    }
}

extern "C" void kernel_launch(void* const* d_in, const int* in_sizes, int n_in,
                              void* d_out, int out_size, void* d_ws, size_t ws_size,
                              hipStream_t stream) {
    const float* y         = (const float*)d_in[0];
    const float* a         = (const float*)d_in[1];
    const float* phi       = (const float*)d_in[2];
    const float* env_knots = (const float*)d_in[3];
    const int*   k_bins    = (const int*)d_in[4];
    float* out = (float*)d_out;
    float* ws  = (float*)d_ws;

    int B = in_sizes[0] / (T_LEN * V_DIM);
    int ids = T_LEN + V_DIM * KBINS + V_DIM * NKNOTS;
    precompute_kernel<<<(ids + 255) / 256, 256, 0, stream>>>(a, phi, env_knots, k_bins, ws);
    coef_kernel<<<B, BLOCK, 0, stream>>>(y, ws, out);
    apply_kernel<<<B, BLOCK, 0, stream>>>(y, ws, out, B);
}